// Round 8
// baseline (476.031 us; speedup 1.0000x reference)
//
#include <hip/hip_runtime.h>
#include <hip/hip_bf16.h>

#define Bb 4
#define Hh 8
#define Ll 8192
#define Dd 64
#define Cc 256
#define Ww 32
#define TL 128     // tokens per k1 block
#define NBLK 64    // Ll / TL tiles per plane
#define CAP2 2048  // k2_sel LDS candidate capacity

// ---------------- k1: dists GEMM (8x8 tile, 2 passes, dists in VGPRs, barrier-free store tail) ----------------
// grid (64, hStep, bStep), block 256. Emits: distT (full), S2 (per-16-token sub-block column maxima),
// buckets, lossP. S2 costs ~512 extra shuffle/max ops/thread (~13% of GEMM FMA) and lets k2 skip ~96%
// of the distT read-back.
__global__ __launch_bounds__(256, 2) void k1_gemm(const float* __restrict__ x,
                                                  const float* __restrict__ means,
                                                  float* __restrict__ distT,
                                                  float* __restrict__ S2,
                                                  int* __restrict__ buckets,
                                                  float* __restrict__ lossP,
                                                  int b0, int h0) {
    __shared__ __align__(16) float ms[128 * 68];   // 34.8 KB
    __shared__ __align__(16) float xs[TL * 68];    // 34.8 KB
    __shared__ float pv[TL * 4];
    __shared__ int   pc[TL * 4];
    __shared__ float msq[256];
    __shared__ float lossAcc;

    const int tid = threadIdx.x;
    const int hl  = blockIdx.y, bz = blockIdx.z;
    const int h   = h0 + hl,    b  = b0 + bz;
    const int l0  = blockIdx.x * TL;
    const int tg  = tid & 15;    // tokens t = tg + 16*jt, jt<8
    const int cg  = tid >> 4;    // clusters c = cg + 16*jl (+128 for pass B), jl<8

    if (tid == 0) lossAcc = 0.f;

    const float* xbase = x + (((size_t)(b * Hh + h)) * Ll + l0) * Dd;
    for (int j = tid; j < TL * 16; j += 256) {
        int t = j >> 4, k4 = (j & 15) << 2;
        *(float4*)&xs[t * 68 + k4] = *(const float4*)(xbase + t * Dd + k4);
    }

    float accA[8][8], accB[8][8];

    // ---- pass A: clusters 0..127 ----
    {
        const float* mbase = means + ((size_t)h * Cc) * Dd;
        for (int j = tid; j < 128 * 16; j += 256) {
            int r = j >> 4, k4 = (j & 15) << 2;
            *(float4*)&ms[r * 68 + k4] = *(const float4*)(mbase + r * Dd + k4);
        }
        __syncthreads();   // covers xs + msA staging
        if (tid < 128) {
            float s = 0.f;
            #pragma unroll
            for (int k = 0; k < 64; k += 4) {
                float4 m = *(const float4*)&ms[tid * 68 + k];
                s = fmaf(m.x, m.x, s); s = fmaf(m.y, m.y, s);
                s = fmaf(m.z, m.z, s); s = fmaf(m.w, m.w, s);
            }
            msq[tid] = s;
        }
        #pragma unroll
        for (int jt = 0; jt < 8; jt++)
            #pragma unroll
            for (int jl = 0; jl < 8; jl++) accA[jt][jl] = 0.f;
        #pragma unroll 4
        for (int k = 0; k < 64; k += 4) {
            float4 xa[8];
            #pragma unroll
            for (int jt = 0; jt < 8; jt++) xa[jt] = *(const float4*)&xs[(tg + 16 * jt) * 68 + k];
            #pragma unroll
            for (int jl = 0; jl < 8; jl++) {
                float4 m = *(const float4*)&ms[(cg + 16 * jl) * 68 + k];
                #pragma unroll
                for (int jt = 0; jt < 8; jt++) {
                    float a = accA[jt][jl];
                    a = fmaf(xa[jt].x, m.x, a); a = fmaf(xa[jt].y, m.y, a);
                    a = fmaf(xa[jt].z, m.z, a); a = fmaf(xa[jt].w, m.w, a);
                    accA[jt][jl] = a;
                }
            }
        }
        __syncthreads();   // all reads of msA done (no stores pending: drain-free)
    }

    // ---- pass B: clusters 128..255 ----
    {
        const float* mbase = means + ((size_t)h * Cc + 128) * Dd;
        for (int j = tid; j < 128 * 16; j += 256) {
            int r = j >> 4, k4 = (j & 15) << 2;
            *(float4*)&ms[r * 68 + k4] = *(const float4*)(mbase + r * Dd + k4);
        }
        __syncthreads();
        if (tid < 128) {
            float s = 0.f;
            #pragma unroll
            for (int k = 0; k < 64; k += 4) {
                float4 m = *(const float4*)&ms[tid * 68 + k];
                s = fmaf(m.x, m.x, s); s = fmaf(m.y, m.y, s);
                s = fmaf(m.z, m.z, s); s = fmaf(m.w, m.w, s);
            }
            msq[128 + tid] = s;
        }
        #pragma unroll
        for (int jt = 0; jt < 8; jt++)
            #pragma unroll
            for (int jl = 0; jl < 8; jl++) accB[jt][jl] = 0.f;
        #pragma unroll 4
        for (int k = 0; k < 64; k += 4) {
            float4 xa[8];
            #pragma unroll
            for (int jt = 0; jt < 8; jt++) xa[jt] = *(const float4*)&xs[(tg + 16 * jt) * 68 + k];
            #pragma unroll
            for (int jl = 0; jl < 8; jl++) {
                float4 m = *(const float4*)&ms[(cg + 16 * jl) * 68 + k];
                #pragma unroll
                for (int jt = 0; jt < 8; jt++) {
                    float a = accB[jt][jl];
                    a = fmaf(xa[jt].x, m.x, a); a = fmaf(xa[jt].y, m.y, a);
                    a = fmaf(xa[jt].z, m.z, a); a = fmaf(xa[jt].w, m.w, a);
                    accB[jt][jl] = a;
                }
            }
        }
    }

    // ---- tail 1: argmax + loss (barriers fire with zero pending stores) ----
    #pragma unroll
    for (int jt = 0; jt < 8; jt++) {
        float bv = -3.4e38f; int bc = 0;
        #pragma unroll
        for (int jl = 0; jl < 8; jl++) {           // ascending c: strict > keeps lowest c
            float v = accA[jt][jl];
            if (v > bv) { bv = v; bc = cg + 16 * jl; }
        }
        #pragma unroll
        for (int jl = 0; jl < 8; jl++) {
            float v = accB[jt][jl];
            if (v > bv) { bv = v; bc = cg + 16 * jl + 128; }
        }
        #pragma unroll
        for (int off = 16; off <= 32; off <<= 1) {
            float ov = __shfl_xor(bv, off);
            int   oc = __shfl_xor(bc, off);
            if (ov > bv || (ov == bv && oc < bc)) { bv = ov; bc = oc; }
        }
        if ((tid & 48) == 0) { int t = tg + 16 * jt; pv[t * 4 + (tid >> 6)] = bv; pc[t * 4 + (tid >> 6)] = bc; }
    }
    __syncthreads();

    if (tid < TL) {
        int t = tid;
        float bv = pv[t * 4]; int bc = pc[t * 4];
        #pragma unroll
        for (int g = 1; g < 4; g++) {
            float v = pv[t * 4 + g]; int c2 = pc[t * 4 + g];
            if (v > bv || (v == bv && c2 < bc)) { bv = v; bc = c2; }
        }
        float ss = 0.f;
        #pragma unroll
        for (int k = 0; k < 64; k += 4) {
            float4 u = *(const float4*)&xs[t * 68 + k];
            ss = fmaf(u.x, u.x, ss); ss = fmaf(u.y, u.y, ss);
            ss = fmaf(u.z, u.z, ss); ss = fmaf(u.w, u.w, ss);
        }
        buckets[((size_t)(b * Hh + h)) * Ll + l0 + t] = bc;
        atomicAdd(&lossAcc, ss - 2.f * bv + msq[bc]);
    }
    __syncthreads();
    if (tid == 0) lossP[(b * Hh + h) * NBLK + blockIdx.x] = lossAcc;

    // ---- tail 2: S2 sub-block maxima (16-token granularity; shuffles only, no barrier) ----
    // sub-block (tile=blockIdx.x, jt) covers tokens [l0 + 16*jt, +16) == the 16 tg lanes.
    const size_t s2row = ((size_t)(bz * gridDim.y + hl)) * Cc;  // plane * Cc
    #pragma unroll
    for (int jl = 0; jl < 8; jl++) {
        float sa[8], sb[8];
        #pragma unroll
        for (int jt = 0; jt < 8; jt++) { sa[jt] = accA[jt][jl]; sb[jt] = accB[jt][jl]; }
        #pragma unroll
        for (int off = 1; off < 16; off <<= 1) {
            #pragma unroll
            for (int jt = 0; jt < 8; jt++) {
                sa[jt] = fmaxf(sa[jt], __shfl_xor(sa[jt], off));
                sb[jt] = fmaxf(sb[jt], __shfl_xor(sb[jt], off));
            }
        }
        if (tg == 0) {
            float* pA = S2 + ((s2row + cg + 16 * jl) * NBLK + blockIdx.x) * 8;
            float* pB = S2 + ((s2row + cg + 16 * jl + 128) * NBLK + blockIdx.x) * 8;
            *(float4*)pA       = make_float4(sa[0], sa[1], sa[2], sa[3]);
            *(float4*)(pA + 4) = make_float4(sa[4], sa[5], sa[6], sa[7]);
            *(float4*)pB       = make_float4(sb[0], sb[1], sb[2], sb[3]);
            *(float4*)(pB + 4) = make_float4(sb[4], sb[5], sb[6], sb[7]);
        }
    }

    // ---- tail 3: all distT stores last; drain at kernel exit ----
    const size_t pbase = ((size_t)(bz * gridDim.y + hl)) * Cc;
    float* dbaseA = distT + (pbase + cg) * Ll + l0 + tg;
    #pragma unroll
    for (int jl = 0; jl < 8; jl++) {
        float* rowA = dbaseA + (size_t)(16 * jl) * Ll;
        float* rowB = dbaseA + (size_t)(16 * jl + 128) * Ll;
        #pragma unroll
        for (int jt = 0; jt < 8; jt++) {
            rowA[16 * jt] = accA[jt][jl];
            rowB[16 * jt] = accB[jt][jl];
        }
    }
}

// ---------------- k2_sel: S2-guided sparse select ----------------
__device__ __forceinline__ unsigned int f2key(float f) {
    unsigned int u = __float_as_uint(f);
    return (u & 0x80000000u) ? ~u : (u | 0x80000000u);
}

// grid (Cc, hStep, bStep), block 256. Derive 64 tile maxima from S2 (max of 8 sub-maxima),
// bitonic -> T = 32nd-largest tile max (field-verified r4-r7: >=32 distinct tokens have
// key >= T => exact candidate superset). Then read ONLY sub-blocks with submax >= T
// (~40 x 64 B per column) instead of the full 32 KB column: ~96% read reduction.
__global__ __launch_bounds__(256) void k2_sel(const float* __restrict__ distT,
                                              const float* __restrict__ S2,
                                              float* __restrict__ outIdx,
                                              int b0, int h0) {
    __shared__ unsigned int sT, sCnt;
    __shared__ unsigned int candK[CAP2];
    __shared__ int candI[CAP2];
    __shared__ int comb[32];

    const int tid = threadIdx.x;
    const int c = blockIdx.x, hl = blockIdx.y, bz = blockIdx.z;
    const int h = h0 + hl, b = b0 + bz;
    const int pl = bz * gridDim.y + hl;                   // pass-local plane
    const float* col = distT + ((size_t)pl * Cc + c) * Ll;
    const float* s2c = S2 + ((size_t)pl * Cc + c) * (NBLK * 8);

    if (tid < 64) {  // tile max = max of its 8 sub-maxima; bitonic-64; 32nd-largest
        float4 v0 = *(const float4*)(s2c + tid * 8);
        float4 v1 = *(const float4*)(s2c + tid * 8 + 4);
        float tm = fmaxf(fmaxf(fmaxf(v0.x, v0.y), fmaxf(v0.z, v0.w)),
                         fmaxf(fmaxf(v1.x, v1.y), fmaxf(v1.z, v1.w)));
        unsigned int k2 = f2key(tm);
        #pragma unroll
        for (int kk = 2; kk <= 64; kk <<= 1) {
            #pragma unroll
            for (int j = kk >> 1; j > 0; j >>= 1) {
                unsigned int o = (unsigned int)__shfl_xor((int)k2, j);
                bool up = ((tid & kk) == 0);
                bool hi = (tid & j) != 0;
                unsigned int mn = k2 < o ? k2 : o;
                unsigned int mx = k2 < o ? o : k2;
                k2 = (up == hi) ? mx : mn;   // ascending within each region
            }
        }
        if (tid == 32) sT = k2;              // ascending lane 32 == 32nd largest
        if (tid == 0)  sCnt = 0u;
    }
    __syncthreads();
    const unsigned int T = sT;

    // sparse candidate scan: only sub-blocks whose submax >= T contain candidates
    for (int s = tid; s < NBLK * 8; s += 256) {
        if (f2key(s2c[s]) >= T) {
            const int ibase = (s >> 3) * 128 + (s & 7) * 16;   // 16 contiguous tokens
            const float* p = col + ibase;
            #pragma unroll
            for (int q = 0; q < 4; q++) {
                float4 v = *(const float4*)(p + q * 4);
                float vv[4] = {v.x, v.y, v.z, v.w};
                #pragma unroll
                for (int e = 0; e < 4; e++) {
                    unsigned int kk = f2key(vv[e]);
                    if (kk >= T) {
                        unsigned pos = atomicAdd(&sCnt, 1u);
                        if (pos < CAP2) { candK[pos] = kk; candI[pos] = ibase + q * 4 + e; }
                    }
                }
            }
        }
    }
    __syncthreads();
    const int cnt = (int)sCnt;

    if (cnt <= CAP2) {
        // exact stable rank among candidates (== global rank for all top-32 elements)
        for (int i = tid; i < cnt; i += 256) {
            unsigned int k = candK[i]; int id = candI[i];
            int rk = 0;
            for (int j2 = 0; j2 < cnt; j2++) {
                unsigned int kj = candK[j2];
                rk += (kj > k || (kj == k && candI[j2] < id)) ? 1 : 0;
            }
            if (rk < 32) comb[rk] = id;
        }
        __syncthreads();
    } else {
        if (tid == 0) {   // pathological tie flood: exact serial stable top-32 from full column
            unsigned int bk[32]; int bi[32];
            for (int j = 0; j < 32; j++) { bk[j] = 0u; bi[j] = 0; }
            for (int i = 0; i < Ll; i++) {
                unsigned int kk = f2key(col[i]);
                if (kk > bk[31]) {
                    int p2 = 31;
                    while (p2 > 0 && kk > bk[p2 - 1]) {
                        bk[p2] = bk[p2 - 1]; bi[p2] = bi[p2 - 1]; p2--;
                    }
                    bk[p2] = kk; bi[p2] = i;
                }
            }
            for (int j = 0; j < 32; j++) comb[j] = bi[j];
        }
        __syncthreads();
    }

    if (tid < Ww) {
        int v = comb[tid];
        int rank = 0;
        #pragma unroll
        for (int j = 0; j < Ww; j++) rank += (comb[j] < v);
        outIdx[(((size_t)(b * Hh + h)) * Cc + c) * Ww + rank] = (float)v;
    }
}

// ---------------- k3: counting sort by (h,cluster), then gather ----------------
__global__ __launch_bounds__(256) void k3_hist(const int* __restrict__ buckets,
                                               unsigned int* __restrict__ hist) {
    __shared__ unsigned int lh[256];
    const int tid = threadIdx.x;
    lh[tid] = 0;
    __syncthreads();
    int i = blockIdx.x * 256 + tid;
    int bk = buckets[i];
    atomicAdd(&lh[bk], 1u);
    __syncthreads();
    int h = (i >> 13) & 7;   // block spans 256 tokens of one (b,h)
    if (lh[tid]) atomicAdd(&hist[h * 256 + tid], lh[tid]);
}

__global__ __launch_bounds__(256) void k3_scan(const unsigned int* __restrict__ hist,
                                               unsigned int* __restrict__ offs,
                                               unsigned int* __restrict__ cursor) {
    __shared__ unsigned int ps[256];
    const int tid = threadIdx.x;
    unsigned int loc[8];
    unsigned s = 0;
    #pragma unroll
    for (int k = 0; k < 8; k++) { loc[k] = hist[tid * 8 + k]; s += loc[k]; }
    ps[tid] = s;
    __syncthreads();
    for (int off = 1; off < 256; off <<= 1) {
        unsigned v = (tid >= off) ? ps[tid - off] : 0;
        __syncthreads();
        ps[tid] += v;
        __syncthreads();
    }
    unsigned base = ps[tid] - s;  // exclusive
    #pragma unroll
    for (int k = 0; k < 8; k++) {
        offs[tid * 8 + k] = base;
        cursor[tid * 8 + k] = base;
        base += loc[k];
    }
    if (tid == 255) offs[2048] = ps[255];
}

__global__ __launch_bounds__(256) void k3_scatter(const int* __restrict__ buckets,
                                                  unsigned int* __restrict__ cursor,
                                                  unsigned int* __restrict__ sortedTok) {
    int i = blockIdx.x * 256 + threadIdx.x;
    int bk = buckets[i];
    int h = (i >> 13) & 7, b = i >> 16, l = i & 8191;
    unsigned pos = atomicAdd(&cursor[h * 256 + bk], 1u);
    sortedTok[pos] = (unsigned)((b << 13) | l);
}

// MLP-restructured gather: lane = (token-slot tl = lane>>4, dim-quad q = lane&15).
__global__ __launch_bounds__(256) void k3_gather(const float* __restrict__ x,
                                                 const float* __restrict__ means,
                                                 const unsigned int* __restrict__ offs,
                                                 const unsigned int* __restrict__ sortedTok,
                                                 float* __restrict__ outMeans) {
    __shared__ __align__(16) float part[4][64];
    const int tid = threadIdx.x;
    const int w = tid >> 6;          // wave 0..3
    const int lane = tid & 63;
    const int tl = lane >> 4;        // token slot within wave 0..3
    const int q  = lane & 15;        // dim quad 0..15 (handles d = 4q..4q+3)
    const int bin = blockIdx.x;
    const int h = bin >> 8, cc = bin & 255;
    const unsigned s0 = offs[bin], s1 = offs[bin + 1];
    const int n = (int)(s1 - s0);

    float4 a0 = make_float4(0.f, 0.f, 0.f, 0.f);
    float4 a1 = make_float4(0.f, 0.f, 0.f, 0.f);
    int j = w * 4 + tl;              // this slot handles j ≡ w*4+tl (mod 16)
    for (; j + 16 < n; j += 32) {    // 2 tokens in flight per slot
        unsigned e0 = sortedTok[s0 + j];
        unsigned e1 = sortedTok[s0 + j + 16];
        const float* p0 = x + (((size_t)((int)(e0 >> 13) * Hh + h)) * Ll + (e0 & 8191)) * Dd + q * 4;
        const float* p1 = x + (((size_t)((int)(e1 >> 13) * Hh + h)) * Ll + (e1 & 8191)) * Dd + q * 4;
        float4 v0 = *(const float4*)p0;
        float4 v1 = *(const float4*)p1;
        a0.x += v0.x; a0.y += v0.y; a0.z += v0.z; a0.w += v0.w;
        a1.x += v1.x; a1.y += v1.y; a1.z += v1.z; a1.w += v1.w;
    }
    for (; j < n; j += 16) {         // at most one leftover token per slot
        unsigned e = sortedTok[s0 + j];
        const float* p = x + (((size_t)((int)(e >> 13) * Hh + h)) * Ll + (e & 8191)) * Dd + q * 4;
        float4 v = *(const float4*)p;
        a0.x += v.x; a0.y += v.y; a0.z += v.z; a0.w += v.w;
    }
    a0.x += a1.x; a0.y += a1.y; a0.z += a1.z; a0.w += a1.w;

    // reduce across the 4 token slots (lane bits 4 and 5)
    #pragma unroll
    for (int off = 16; off <= 32; off <<= 1) {
        a0.x += __shfl_xor(a0.x, off);
        a0.y += __shfl_xor(a0.y, off);
        a0.z += __shfl_xor(a0.z, off);
        a0.w += __shfl_xor(a0.w, off);
    }
    if (tl == 0) *(float4*)&part[w][q * 4] = a0;
    __syncthreads();

    if (tid < 64) {
        const int d = tid;
        float s = part[0][d] + part[1][d] + part[2][d] + part[3][d];
        float t = s * s;
        #pragma unroll
        for (int off = 32; off; off >>= 1) t += __shfl_xor(t, off);
        float nrm = sqrtf(t);
        float outv = (n == 0) ? means[((size_t)(h * Cc + cc)) * Dd + d]
                              : s / fmaxf(nrm, 1e-12f);
        outMeans[((size_t)(h * Cc + cc)) * Dd + d] = outv;
    }
}

// ---------------- k4: loss reduction ----------------
__global__ __launch_bounds__(256) void k4_loss(const float* __restrict__ lossP,
                                               float* __restrict__ out) {
    __shared__ float red[256];
    const int tid = threadIdx.x;
    float s = 0.f;
    for (int i = tid; i < Bb * Hh * NBLK; i += 256) s += lossP[i];
    red[tid] = s;
    __syncthreads();
    for (int off = 128; off; off >>= 1) {
        if (tid < off) red[tid] += red[tid + off];
        __syncthreads();
    }
    if (tid == 0)
        out[(size_t)Bb * Hh * Cc * Ww] = red[0] * (1e-4f / (float)((size_t)Bb * Hh * Ll * Dd));
}

extern "C" void kernel_launch(void* const* d_in, const int* in_sizes, int n_in,
                              void* d_out, int out_size, void* d_ws, size_t ws_size,
                              hipStream_t stream) {
    (void)in_sizes; (void)n_in; (void)out_size;
    const float* x = (const float*)d_in[0];
    const float* means = (const float*)d_in[1];
    float* out = (float*)d_out;

    char* ws = (char*)d_ws;
    float* lossP = (float*)ws;                              // 2048 floats (8 KB)
    int* buckets = (int*)(ws + 8192);                       // 1 MB
    unsigned int* hist = (unsigned int*)(ws + 8192 + 1048576);       // 2048
    unsigned int* offs = hist + 2048;                       // 2049
    unsigned int* cursor = offs + 2049;                     // 2048
    unsigned int* sortedTok = cursor + 2048;                // 262144 (1 MB)
    size_t base = 8192 + 1048576 + 4ull * (2048 + 2049 + 2048) + 4ull * 262144;
    base = (base + 255) & ~255ull;
    float* S2 = (float*)(ws + base);                        // 32 planes * 256 cols * 512 f = 16 MB (max)
    size_t dbase = base + 4ull * 32 * Cc * (NBLK * 8);
    dbase = (dbase + 255) & ~255ull;
    float* distT = (float*)(ws + dbase);
    const size_t perPlane = (size_t)Cc * Ll * 4;            // 8 MB per (b,h) plane

    int bStep = 4, hStep = 8;
    if (dbase + (size_t)bStep * hStep * perPlane > ws_size) bStep = 1;
    while (hStep > 1 && dbase + (size_t)bStep * hStep * perPlane > ws_size) hStep >>= 1;

    hipMemsetAsync(hist, 0, 2048 * 4, stream);

    const int IDXN = Bb * Hh * Cc * Ww;  // 262144
    for (int b0 = 0; b0 < Bb; b0 += bStep) {
        for (int h0 = 0; h0 < Hh; h0 += hStep) {
            k1_gemm<<<dim3(NBLK, hStep, bStep), 256, 0, stream>>>(x, means, distT, S2, buckets, lossP, b0, h0);
            k2_sel<<<dim3(Cc, hStep, bStep), 256, 0, stream>>>(distT, S2, out, b0, h0);
        }
    }
    k3_hist<<<1024, 256, 0, stream>>>(buckets, hist);
    k3_scan<<<1, 256, 0, stream>>>(hist, offs, cursor);
    k3_scatter<<<1024, 256, 0, stream>>>(buckets, cursor, sortedTok);
    k3_gather<<<Hh * Cc, 256, 0, stream>>>(x, means, offs, sortedTok, out + IDXN + 1);
    k4_loss<<<1, 256, 0, stream>>>(lossP, out);
}